// Round 1
// baseline (1753.010 us; speedup 1.0000x reference)
//
#include <hip/hip_runtime.h>

#define NN 100000
#define EE 800000
#define HH 128
#define LL 4
#define GG 64
#define BN_EPS 1e-5f
#define LN_EPS 1e-5f
#define TILE_R 128
#define BK 32
#define POOL_CHUNK 512

// ---------------- CSR build ----------------

__global__ void count_deg(const int* __restrict__ ei, int* __restrict__ deg) {
    int e = blockIdx.x * blockDim.x + threadIdx.x;
    if (e >= 2 * EE) return;
    int r = ei[e];
    int c = (e < EE) ? ei[e + EE] : ei[e - EE];
    if (r != c) atomicAdd(&deg[r], 1);
}

// block scans 1024 elements (256 threads x 4)
__global__ void scan_block(const int* __restrict__ deg, int* __restrict__ rp, int* __restrict__ bsum) {
    __shared__ int sh[256];
    int b = blockIdx.x, t = threadIdx.x;
    int base = b * 1024 + t * 4;
    int v[4]; int s = 0;
#pragma unroll
    for (int i = 0; i < 4; i++) { int idx = base + i; v[i] = (idx < NN) ? deg[idx] : 0; s += v[i]; }
    sh[t] = s; __syncthreads();
    for (int off = 1; off < 256; off <<= 1) {
        int x = (t >= off) ? sh[t - off] : 0;
        __syncthreads();
        sh[t] += x;
        __syncthreads();
    }
    int run = (t > 0) ? sh[t - 1] : 0;
#pragma unroll
    for (int i = 0; i < 4; i++) { int idx = base + i; if (idx < NN) rp[idx] = run; run += v[i]; }
    if (t == 255) bsum[b] = sh[255];
}

__global__ void scan_bsum(int* __restrict__ bsum, int* __restrict__ boff, int* __restrict__ rp_last, int nb) {
    __shared__ int sh[128];
    int t = threadIdx.x;
    sh[t] = (t < nb) ? bsum[t] : 0;
    __syncthreads();
    for (int off = 1; off < 128; off <<= 1) {
        int x = (t >= off) ? sh[t - off] : 0;
        __syncthreads();
        sh[t] += x;
        __syncthreads();
    }
    if (t < nb) boff[t] = (t > 0) ? sh[t - 1] : 0;
    if (t == 0) rp_last[0] = sh[127];
}

__global__ void scan_add(int* __restrict__ rp, const int* __restrict__ boff) {
    int i = blockIdx.x * blockDim.x + threadIdx.x;
    if (i < NN) rp[i] += boff[i >> 10];
}

__global__ void fill_csr(const int* __restrict__ ei, const int* __restrict__ rp,
                         int* __restrict__ cursor, int* __restrict__ colidx) {
    int e = blockIdx.x * blockDim.x + threadIdx.x;
    if (e >= 2 * EE) return;
    int r = ei[e];
    int c = (e < EE) ? ei[e + EE] : ei[e - EE];
    if (r != c) {
        int p = atomicAdd(&cursor[r], 1);
        colidx[rp[r] + p] = c;
    }
}

// ---------------- aggregation: u = (1+eps)*h + sum_nb h[nb] ----------------
// one wave per node, 2 floats per lane

__global__ __launch_bounds__(256) void agg_kernel(
    const float* __restrict__ h, const int* __restrict__ rp, const int* __restrict__ colidx,
    const float* __restrict__ eps_l, int layer, float* __restrict__ u)
{
    int node = blockIdx.x * 4 + (threadIdx.x >> 6);
    if (node >= NN) return;
    int lane = threadIdx.x & 63;
    float eps1 = 1.0f + eps_l[layer];
    float2 acc = ((const float2*)(h + (size_t)node * HH))[lane];
    acc.x *= eps1; acc.y *= eps1;
    int i = rp[node], end = rp[node + 1];
    for (; i + 4 <= end; i += 4) {
        int c0 = colidx[i], c1 = colidx[i + 1], c2 = colidx[i + 2], c3 = colidx[i + 3];
        float2 v0 = ((const float2*)(h + (size_t)c0 * HH))[lane];
        float2 v1 = ((const float2*)(h + (size_t)c1 * HH))[lane];
        float2 v2 = ((const float2*)(h + (size_t)c2 * HH))[lane];
        float2 v3 = ((const float2*)(h + (size_t)c3 * HH))[lane];
        acc.x += v0.x + v1.x + v2.x + v3.x;
        acc.y += v0.y + v1.y + v2.y + v3.y;
    }
    for (; i < end; i++) {
        int c = colidx[i];
        float2 v = ((const float2*)(h + (size_t)c * HH))[lane];
        acc.x += v.x; acc.y += v.y;
    }
    ((float2*)(u + (size_t)node * HH))[lane] = acc;
}

// ---------------- GEMM: Out = A @ W + bias (optionally accumulate col stats) ----------------
// block = 512 threads, tile 128 rows x 128 cols, thread tile 4x8, K chunked by 32.
// Safe for Out == A (all A reads into LDS complete before any Out write).

template<bool STATS>
__global__ __launch_bounds__(512) void gemm_k(
    const float* A, const float* __restrict__ W, const float* __restrict__ bias,
    float* Out, float* __restrict__ colsum, float* __restrict__ colsq)
{
    __shared__ float Al[TILE_R][BK + 4];
    __shared__ float Wl[BK][HH];
    __shared__ float csum[HH], csq[HH];
    int tid = threadIdx.x;
    int r0 = blockIdx.x * TILE_R;
    int tr = tid >> 4, tc = tid & 15;
    if (STATS && tid < HH) { csum[tid] = 0.f; csq[tid] = 0.f; }
    float acc[4][8];
#pragma unroll
    for (int j = 0; j < 8; j++) {
        float bv = bias[8 * tc + j];
        acc[0][j] = bv; acc[1][j] = bv; acc[2][j] = bv; acc[3][j] = bv;
    }
    for (int kc = 0; kc < HH; kc += BK) {
#pragma unroll
        for (int s = 0; s < 2; s++) {
            int i = tid + s * 512;
            int r = i >> 3, k4 = (i & 7) << 2;
            int rr = r0 + r;
            float4 v = (rr < NN) ? *(const float4*)(A + (size_t)rr * HH + kc + k4)
                                 : make_float4(0.f, 0.f, 0.f, 0.f);
            *(float4*)&Al[r][k4] = v;
            int wk = i >> 5, wc = (i & 31) << 2;
            *(float4*)&Wl[wk][wc] = *(const float4*)(W + (size_t)(kc + wk) * HH + wc);
        }
        __syncthreads();
#pragma unroll
        for (int k = 0; k < BK; k += 4) {
            float4 a0 = *(float4*)&Al[4 * tr + 0][k];
            float4 a1 = *(float4*)&Al[4 * tr + 1][k];
            float4 a2 = *(float4*)&Al[4 * tr + 2][k];
            float4 a3 = *(float4*)&Al[4 * tr + 3][k];
#pragma unroll
            for (int m = 0; m < 4; m++) {
                float4 bl = *(float4*)&Wl[k + m][8 * tc];
                float4 bh = *(float4*)&Wl[k + m][8 * tc + 4];
                float am0 = ((float*)&a0)[m], am1 = ((float*)&a1)[m];
                float am2 = ((float*)&a2)[m], am3 = ((float*)&a3)[m];
                acc[0][0] += am0 * bl.x; acc[0][1] += am0 * bl.y; acc[0][2] += am0 * bl.z; acc[0][3] += am0 * bl.w;
                acc[0][4] += am0 * bh.x; acc[0][5] += am0 * bh.y; acc[0][6] += am0 * bh.z; acc[0][7] += am0 * bh.w;
                acc[1][0] += am1 * bl.x; acc[1][1] += am1 * bl.y; acc[1][2] += am1 * bl.z; acc[1][3] += am1 * bl.w;
                acc[1][4] += am1 * bh.x; acc[1][5] += am1 * bh.y; acc[1][6] += am1 * bh.z; acc[1][7] += am1 * bh.w;
                acc[2][0] += am2 * bl.x; acc[2][1] += am2 * bl.y; acc[2][2] += am2 * bl.z; acc[2][3] += am2 * bl.w;
                acc[2][4] += am2 * bh.x; acc[2][5] += am2 * bh.y; acc[2][6] += am2 * bh.z; acc[2][7] += am2 * bh.w;
                acc[3][0] += am3 * bl.x; acc[3][1] += am3 * bl.y; acc[3][2] += am3 * bl.z; acc[3][3] += am3 * bl.w;
                acc[3][4] += am3 * bh.x; acc[3][5] += am3 * bh.y; acc[3][6] += am3 * bh.z; acc[3][7] += am3 * bh.w;
            }
        }
        __syncthreads();
    }
#pragma unroll
    for (int i = 0; i < 4; i++) {
        int rr = r0 + 4 * tr + i;
        if (rr < NN) {
            float4* o = (float4*)(Out + (size_t)rr * HH + 8 * tc);
            o[0] = make_float4(acc[i][0], acc[i][1], acc[i][2], acc[i][3]);
            o[1] = make_float4(acc[i][4], acc[i][5], acc[i][6], acc[i][7]);
        }
    }
    if (STATS) {
#pragma unroll
        for (int j = 0; j < 8; j++) {
            float ps = 0.f, pq = 0.f;
#pragma unroll
            for (int i = 0; i < 4; i++) {
                int rr = r0 + 4 * tr + i;
                if (rr < NN) { float z = acc[i][j]; ps += z; pq += z * z; }
            }
            atomicAdd(&csum[8 * tc + j], ps);
            atomicAdd(&csq[8 * tc + j], pq);
        }
        __syncthreads();
        if (tid < HH) {
            atomicAdd(&colsum[tid], csum[tid]);
            atomicAdd(&colsq[tid], csq[tid]);
        }
    }
}

__global__ void bn_finalize(const float* __restrict__ colsum, const float* __restrict__ colsq,
                            const float* __restrict__ bng, const float* __restrict__ bnb,
                            float* __restrict__ scale, float* __restrict__ shift)
{
    int c = threadIdx.x;
    float m = colsum[c] * (1.f / NN);
    float v = colsq[c] * (1.f / NN) - m * m;
    float a = bng[c] * rsqrtf(v + BN_EPS);
    scale[c] = a;
    shift[c] = bnb[c] - m * a;
}

// ---------------- GEMM2 fused: h = LN(h + relu(relu(z1*scale+shift) @ W2 + b2)) ----------------

__global__ __launch_bounds__(512) void gemm2_ln_k(
    const float* __restrict__ Z, const float* __restrict__ W, const float* __restrict__ bias,
    const float* __restrict__ scale, const float* __restrict__ shift,
    const float* __restrict__ lng, const float* __restrict__ lnb,
    float* Hbuf)
{
    __shared__ float Al[TILE_R][BK + 4];
    __shared__ float Wl[BK][HH];
    __shared__ float rsum[TILE_R], rsq[TILE_R];
    int tid = threadIdx.x;
    int r0 = blockIdx.x * TILE_R;
    int tr = tid >> 4, tc = tid & 15;
    if (tid < TILE_R) { rsum[tid] = 0.f; rsq[tid] = 0.f; }
    float acc[4][8];
#pragma unroll
    for (int j = 0; j < 8; j++) {
        float bv = bias[8 * tc + j];
        acc[0][j] = bv; acc[1][j] = bv; acc[2][j] = bv; acc[3][j] = bv;
    }
    for (int kc = 0; kc < HH; kc += BK) {
#pragma unroll
        for (int s = 0; s < 2; s++) {
            int i = tid + s * 512;
            int r = i >> 3, k4 = (i & 7) << 2;
            int rr = r0 + r;
            float4 v = (rr < NN) ? *(const float4*)(Z + (size_t)rr * HH + kc + k4)
                                 : make_float4(0.f, 0.f, 0.f, 0.f);
            float4 sc = *(const float4*)(scale + kc + k4);
            float4 sh = *(const float4*)(shift + kc + k4);
            v.x = fmaxf(fmaf(v.x, sc.x, sh.x), 0.f);
            v.y = fmaxf(fmaf(v.y, sc.y, sh.y), 0.f);
            v.z = fmaxf(fmaf(v.z, sc.z, sh.z), 0.f);
            v.w = fmaxf(fmaf(v.w, sc.w, sh.w), 0.f);
            *(float4*)&Al[r][k4] = v;
            int wk = i >> 5, wc = (i & 31) << 2;
            *(float4*)&Wl[wk][wc] = *(const float4*)(W + (size_t)(kc + wk) * HH + wc);
        }
        __syncthreads();
#pragma unroll
        for (int k = 0; k < BK; k += 4) {
            float4 a0 = *(float4*)&Al[4 * tr + 0][k];
            float4 a1 = *(float4*)&Al[4 * tr + 1][k];
            float4 a2 = *(float4*)&Al[4 * tr + 2][k];
            float4 a3 = *(float4*)&Al[4 * tr + 3][k];
#pragma unroll
            for (int m = 0; m < 4; m++) {
                float4 bl = *(float4*)&Wl[k + m][8 * tc];
                float4 bh = *(float4*)&Wl[k + m][8 * tc + 4];
                float am0 = ((float*)&a0)[m], am1 = ((float*)&a1)[m];
                float am2 = ((float*)&a2)[m], am3 = ((float*)&a3)[m];
                acc[0][0] += am0 * bl.x; acc[0][1] += am0 * bl.y; acc[0][2] += am0 * bl.z; acc[0][3] += am0 * bl.w;
                acc[0][4] += am0 * bh.x; acc[0][5] += am0 * bh.y; acc[0][6] += am0 * bh.z; acc[0][7] += am0 * bh.w;
                acc[1][0] += am1 * bl.x; acc[1][1] += am1 * bl.y; acc[1][2] += am1 * bl.z; acc[1][3] += am1 * bl.w;
                acc[1][4] += am1 * bh.x; acc[1][5] += am1 * bh.y; acc[1][6] += am1 * bh.z; acc[1][7] += am1 * bh.w;
                acc[2][0] += am2 * bl.x; acc[2][1] += am2 * bl.y; acc[2][2] += am2 * bl.z; acc[2][3] += am2 * bl.w;
                acc[2][4] += am2 * bh.x; acc[2][5] += am2 * bh.y; acc[2][6] += am2 * bh.z; acc[2][7] += am2 * bh.w;
                acc[3][0] += am3 * bl.x; acc[3][1] += am3 * bl.y; acc[3][2] += am3 * bl.z; acc[3][3] += am3 * bl.w;
                acc[3][4] += am3 * bh.x; acc[3][5] += am3 * bh.y; acc[3][6] += am3 * bh.z; acc[3][7] += am3 * bh.w;
            }
        }
        __syncthreads();
    }
    // t = h_old + relu(acc); per-row LN
    float tvals[4][8];
#pragma unroll
    for (int i = 0; i < 4; i++) {
        int rr = r0 + 4 * tr + i;
        if (rr < NN) {
            float4 h0 = *(const float4*)(Hbuf + (size_t)rr * HH + 8 * tc);
            float4 h1 = *(const float4*)(Hbuf + (size_t)rr * HH + 8 * tc + 4);
            float hv[8] = {h0.x, h0.y, h0.z, h0.w, h1.x, h1.y, h1.z, h1.w};
            float ps = 0.f, pq = 0.f;
#pragma unroll
            for (int j = 0; j < 8; j++) {
                float t = hv[j] + fmaxf(acc[i][j], 0.f);
                tvals[i][j] = t; ps += t; pq += t * t;
            }
            atomicAdd(&rsum[4 * tr + i], ps);
            atomicAdd(&rsq[4 * tr + i], pq);
        }
    }
    __syncthreads();
#pragma unroll
    for (int i = 0; i < 4; i++) {
        int rr = r0 + 4 * tr + i;
        if (rr < NN) {
            float mu = rsum[4 * tr + i] * (1.f / 128.f);
            float var = rsq[4 * tr + i] * (1.f / 128.f) - mu * mu;
            float rs = rsqrtf(var + LN_EPS);
            float o[8];
#pragma unroll
            for (int j = 0; j < 8; j++) {
                int c = 8 * tc + j;
                o[j] = (tvals[i][j] - mu) * rs * lng[c] + lnb[c];
            }
            float4* op = (float4*)(Hbuf + (size_t)rr * HH + 8 * tc);
            op[0] = make_float4(o[0], o[1], o[2], o[3]);
            op[1] = make_float4(o[4], o[5], o[6], o[7]);
        }
    }
}

// ---------------- pooling ----------------

__global__ void pool_kernel(const float* __restrict__ h, const int* __restrict__ batch,
                            float* __restrict__ psum, float* __restrict__ pcnt)
{
    int t = threadIdx.x;  // 128
    int n0 = blockIdx.x * POOL_CHUNK;
    int n1 = n0 + POOL_CHUNK; if (n1 > NN) n1 = NN;
    float acc = 0.f;
    int cur = batch[n0];
    int cnt = 0;
    for (int n = n0; n < n1; n++) {
        int g = batch[n];
        if (g != cur) {
            atomicAdd(&psum[cur * HH + t], acc);
            if (t == 0) atomicAdd(&pcnt[cur], (float)cnt);
            acc = 0.f; cnt = 0; cur = g;
        }
        acc += h[(size_t)n * HH + t];
        cnt++;
    }
    atomicAdd(&psum[cur * HH + t], acc);
    if (t == 0) atomicAdd(&pcnt[cur], (float)cnt);
}

__global__ void pool_final(const float* __restrict__ psum, const float* __restrict__ pcnt,
                           float* __restrict__ out)
{
    int i = blockIdx.x * blockDim.x + threadIdx.x;
    if (i < GG * HH) {
        float c = pcnt[i >> 7];
        out[i] = psum[i] / fmaxf(c, 1.f);
    }
}

// ---------------- launch ----------------

extern "C" void kernel_launch(void* const* d_in, const int* in_sizes, int n_in,
                              void* d_out, int out_size, void* d_ws, size_t ws_size,
                              hipStream_t stream)
{
    const float* x     = (const float*)d_in[0];
    const float* W0    = (const float*)d_in[1];
    const float* b0    = (const float*)d_in[2];
    const float* eps_l = (const float*)d_in[3];
    const float* W1    = (const float*)d_in[4];
    const float* b1    = (const float*)d_in[5];
    const float* bng   = (const float*)d_in[6];
    const float* bnb   = (const float*)d_in[7];
    const float* W2    = (const float*)d_in[8];
    const float* b2    = (const float*)d_in[9];
    const float* lng   = (const float*)d_in[10];
    const float* lnb   = (const float*)d_in[11];
    const int*   ei    = (const int*)d_in[12];
    const int*   batch = (const int*)d_in[13];
    float* out = (float*)d_out;

    char* ws = (char*)d_ws;
    size_t off = 0;
    auto alloc = [&](size_t bytes) -> void* {
        void* p = ws + off;
        off += (bytes + 255) & ~(size_t)255;
        return p;
    };
    float* hbuf   = (float*)alloc((size_t)NN * HH * 4);
    float* ubuf   = (float*)alloc((size_t)NN * HH * 4);
    int*   colidx = (int*)alloc((size_t)2 * EE * 4);
    int*   rp     = (int*)alloc((size_t)(NN + 1) * 4);
    int*   deg    = (int*)alloc((size_t)NN * 4);
    int*   cursor = (int*)alloc((size_t)NN * 4);
    int*   bsum   = (int*)alloc(128 * 4);
    int*   boff   = (int*)alloc(128 * 4);
    float* colsum = (float*)alloc(HH * 4);
    float* colsq  = (float*)alloc(HH * 4);
    float* bn_sc  = (float*)alloc(HH * 4);
    float* bn_sh  = (float*)alloc(HH * 4);
    float* psum   = (float*)alloc((size_t)GG * HH * 4);
    float* pcnt   = (float*)alloc(GG * 4);

    hipMemsetAsync(deg, 0, (size_t)NN * 4, stream);
    hipMemsetAsync(cursor, 0, (size_t)NN * 4, stream);
    hipMemsetAsync(psum, 0, (size_t)GG * HH * 4, stream);
    hipMemsetAsync(pcnt, 0, (size_t)GG * 4, stream);

    // CSR build
    count_deg<<<(2 * EE + 255) / 256, 256, 0, stream>>>(ei, deg);
    scan_block<<<(NN + 1023) / 1024, 256, 0, stream>>>(deg, rp, bsum);
    scan_bsum<<<1, 128, 0, stream>>>(bsum, boff, rp + NN, (NN + 1023) / 1024);
    scan_add<<<(NN + 255) / 256, 256, 0, stream>>>(rp, boff);
    fill_csr<<<(2 * EE + 255) / 256, 256, 0, stream>>>(ei, rp, cursor, colidx);

    int gb = (NN + TILE_R - 1) / TILE_R;
    // encode: h = x @ W0 + b0
    gemm_k<false><<<gb, 512, 0, stream>>>(x, W0, b0, hbuf, nullptr, nullptr);

    for (int l = 0; l < LL; l++) {
        agg_kernel<<<(NN + 3) / 4, 256, 0, stream>>>(hbuf, rp, colidx, eps_l, l, ubuf);
        hipMemsetAsync(colsum, 0, HH * 4, stream);
        hipMemsetAsync(colsq, 0, HH * 4, stream);
        // z1 = u @ W1 + b1 (in-place into ubuf) + column stats
        gemm_k<true><<<gb, 512, 0, stream>>>(ubuf, W1 + (size_t)l * HH * HH, b1 + l * HH,
                                             ubuf, colsum, colsq);
        bn_finalize<<<1, 128, 0, stream>>>(colsum, colsq, bng + l * HH, bnb + l * HH, bn_sc, bn_sh);
        // h = LN(h + relu(relu(BN(z1)) @ W2 + b2))
        gemm2_ln_k<<<gb, 512, 0, stream>>>(ubuf, W2 + (size_t)l * HH * HH, b2 + l * HH,
                                           bn_sc, bn_sh, lng + l * HH, lnb + l * HH, hbuf);
    }

    pool_kernel<<<(NN + POOL_CHUNK - 1) / POOL_CHUNK, 128, 0, stream>>>(hbuf, batch, psum, pcnt);
    pool_final<<<(GG * HH + 255) / 256, 256, 0, stream>>>(psum, pcnt, out);
}

// Round 2
// 1353.006 us; speedup vs baseline: 1.2956x; 1.2956x over previous
//
#include <hip/hip_runtime.h>

#define NN 100000
#define EE 800000
#define HH 128
#define LL 4
#define GG 64
#define BN_EPS 1e-5f
#define LN_EPS 1e-5f
#define POOL_CHUNK 64

typedef __attribute__((ext_vector_type(8))) short short8;
typedef __attribute__((ext_vector_type(4))) float f32x4;

__device__ inline unsigned short bf16_rne(float f) {
    unsigned u = __float_as_uint(f);
    return (unsigned short)((u + 0x7FFF + ((u >> 16) & 1)) >> 16);
}
__device__ inline float bf16_to_f32(unsigned short h) {
    return __uint_as_float((unsigned)h << 16);
}

// ---------------- CSR build ----------------

__global__ void count_deg(const int* __restrict__ ei, int* __restrict__ deg) {
    int e = blockIdx.x * blockDim.x + threadIdx.x;
    if (e >= 2 * EE) return;
    int r = ei[e];
    int c = (e < EE) ? ei[e + EE] : ei[e - EE];
    if (r != c) atomicAdd(&deg[r], 1);
}

__global__ void scan_block(const int* __restrict__ deg, int* __restrict__ rp, int* __restrict__ bsum) {
    __shared__ int sh[256];
    int b = blockIdx.x, t = threadIdx.x;
    int base = b * 1024 + t * 4;
    int v[4]; int s = 0;
#pragma unroll
    for (int i = 0; i < 4; i++) { int idx = base + i; v[i] = (idx < NN) ? deg[idx] : 0; s += v[i]; }
    sh[t] = s; __syncthreads();
    for (int off = 1; off < 256; off <<= 1) {
        int x = (t >= off) ? sh[t - off] : 0;
        __syncthreads();
        sh[t] += x;
        __syncthreads();
    }
    int run = (t > 0) ? sh[t - 1] : 0;
#pragma unroll
    for (int i = 0; i < 4; i++) { int idx = base + i; if (idx < NN) rp[idx] = run; run += v[i]; }
    if (t == 255) bsum[b] = sh[255];
}

__global__ void scan_bsum(int* __restrict__ bsum, int* __restrict__ boff, int* __restrict__ rp_last, int nb) {
    __shared__ int sh[128];
    int t = threadIdx.x;
    sh[t] = (t < nb) ? bsum[t] : 0;
    __syncthreads();
    for (int off = 1; off < 128; off <<= 1) {
        int x = (t >= off) ? sh[t - off] : 0;
        __syncthreads();
        sh[t] += x;
        __syncthreads();
    }
    if (t < nb) boff[t] = (t > 0) ? sh[t - 1] : 0;
    if (t == 0) rp_last[0] = sh[127];
}

__global__ void scan_add(int* __restrict__ rp, const int* __restrict__ boff) {
    int i = blockIdx.x * blockDim.x + threadIdx.x;
    if (i < NN) rp[i] += boff[i >> 10];
}

__global__ void fill_csr(const int* __restrict__ ei, const int* __restrict__ rp,
                         int* __restrict__ cursor, int* __restrict__ colidx) {
    int e = blockIdx.x * blockDim.x + threadIdx.x;
    if (e >= 2 * EE) return;
    int r = ei[e];
    int c = (e < EE) ? ei[e + EE] : ei[e - EE];
    if (r != c) {
        int p = atomicAdd(&cursor[r], 1);
        colidx[rp[r] + p] = c;
    }
}

// ---------------- weight prep: transpose + split fp32 -> bf16 hi/lo ----------------
// layout: wt[mat][n][k], mat: 0=W0, 1..4=W1[l], 5..8=W2[l]

__global__ void prep_w(const float* __restrict__ W0, const float* __restrict__ W1,
                       const float* __restrict__ W2,
                       short* __restrict__ wt_hi, short* __restrict__ wt_lo) {
    int i = blockIdx.x * 256 + threadIdx.x;
    if (i >= 9 * HH * HH) return;
    int mat = i >> 14, rem = i & 16383;
    int n = rem >> 7, k = rem & 127;
    const float* src = (mat == 0) ? W0 : ((mat <= 4) ? W1 + (size_t)(mat - 1) * HH * HH
                                                     : W2 + (size_t)(mat - 5) * HH * HH);
    float v = src[(size_t)k * HH + n];
    unsigned short h = bf16_rne(v);
    wt_hi[i] = (short)h;
    wt_lo[i] = (short)bf16_rne(v - bf16_to_f32(h));
}

// ---------------- aggregation: u = (1+eps)*h + sum_nb h[nb] ----------------

__global__ __launch_bounds__(256) void agg_kernel(
    const float* __restrict__ h, const int* __restrict__ rp, const int* __restrict__ colidx,
    const float* __restrict__ eps_l, int layer, float* __restrict__ u)
{
    int node = blockIdx.x * 4 + (threadIdx.x >> 6);
    if (node >= NN) return;
    int lane = threadIdx.x & 63;
    float eps1 = 1.0f + eps_l[layer];
    float2 acc = ((const float2*)(h + (size_t)node * HH))[lane];
    acc.x *= eps1; acc.y *= eps1;
    int i = rp[node], end = rp[node + 1];
    for (; i + 4 <= end; i += 4) {
        int c0 = colidx[i], c1 = colidx[i + 1], c2 = colidx[i + 2], c3 = colidx[i + 3];
        float2 v0 = ((const float2*)(h + (size_t)c0 * HH))[lane];
        float2 v1 = ((const float2*)(h + (size_t)c1 * HH))[lane];
        float2 v2 = ((const float2*)(h + (size_t)c2 * HH))[lane];
        float2 v3 = ((const float2*)(h + (size_t)c3 * HH))[lane];
        acc.x += v0.x + v1.x + v2.x + v3.x;
        acc.y += v0.y + v1.y + v2.y + v3.y;
    }
    for (; i < end; i++) {
        int c = colidx[i];
        float2 v = ((const float2*)(h + (size_t)c * HH))[lane];
        acc.x += v.x; acc.y += v.y;
    }
    ((float2*)(u + (size_t)node * HH))[lane] = acc;
}

// ---------------- MFMA GEMM, split-bf16 (hi+lo), K=N=128 ----------------
// block = 256 (4 waves); each wave: 32 rows x 128 cols = 2x8 tiles of 16x16x32.
// MODE 0: Out = A@W + bias
// MODE 1: Out = A@W + bias, accumulate column sum/sumsq (BN stats)
// MODE 2: A' = relu(A*sc + sh);  Hbuf = LN(Hbuf + relu(A'@W + bias))

template<int MODE>
__global__ __launch_bounds__(256) void mfma_gemm(
    const float* __restrict__ A, const short* __restrict__ wt_hi, const short* __restrict__ wt_lo,
    const float* __restrict__ bias, float* __restrict__ Out,
    float* __restrict__ colsum, float* __restrict__ colsq,
    const float* __restrict__ sc, const float* __restrict__ sh,
    const float* __restrict__ lng, const float* __restrict__ lnb,
    float* __restrict__ Hbuf)
{
    __shared__ float csum[HH], csq[HH];
    int tid = threadIdx.x;
    int wave = tid >> 6, lane = tid & 63;
    int lrow = lane & 15, kgrp = lane >> 4;
    int r0 = blockIdx.x * 128 + wave * 32;
    if (MODE == 1) {
        if (tid < HH) { csum[tid] = 0.f; csq[tid] = 0.f; }
        __syncthreads();
    }
    f32x4 acc[2][8];
#pragma unroll
    for (int t = 0; t < 2; t++)
#pragma unroll
        for (int c = 0; c < 8; c++) acc[t][c] = (f32x4){0.f, 0.f, 0.f, 0.f};

#pragma unroll
    for (int ks = 0; ks < 4; ks++) {
        int kb = ks * 32 + kgrp * 8;
        float4 scv0, scv1, shv0, shv1;
        if (MODE == 2) {
            scv0 = *(const float4*)(sc + kb); scv1 = *(const float4*)(sc + kb + 4);
            shv0 = *(const float4*)(sh + kb); shv1 = *(const float4*)(sh + kb + 4);
        }
        short8 ahi[2], alo[2];
#pragma unroll
        for (int t = 0; t < 2; t++) {
            int row = r0 + t * 16 + lrow;
            float av[8];
            if (row < NN) {
                float4 p0 = *(const float4*)(A + (size_t)row * HH + kb);
                float4 p1 = *(const float4*)(A + (size_t)row * HH + kb + 4);
                av[0] = p0.x; av[1] = p0.y; av[2] = p0.z; av[3] = p0.w;
                av[4] = p1.x; av[5] = p1.y; av[6] = p1.z; av[7] = p1.w;
            } else {
#pragma unroll
                for (int j = 0; j < 8; j++) av[j] = 0.f;
            }
            if (MODE == 2) {
                av[0] = fmaxf(fmaf(av[0], scv0.x, shv0.x), 0.f);
                av[1] = fmaxf(fmaf(av[1], scv0.y, shv0.y), 0.f);
                av[2] = fmaxf(fmaf(av[2], scv0.z, shv0.z), 0.f);
                av[3] = fmaxf(fmaf(av[3], scv0.w, shv0.w), 0.f);
                av[4] = fmaxf(fmaf(av[4], scv1.x, shv1.x), 0.f);
                av[5] = fmaxf(fmaf(av[5], scv1.y, shv1.y), 0.f);
                av[6] = fmaxf(fmaf(av[6], scv1.z, shv1.z), 0.f);
                av[7] = fmaxf(fmaf(av[7], scv1.w, shv1.w), 0.f);
            }
#pragma unroll
            for (int j = 0; j < 8; j++) {
                unsigned short hb = bf16_rne(av[j]);
                ahi[t][j] = (short)hb;
                alo[t][j] = (short)bf16_rne(av[j] - bf16_to_f32(hb));
            }
        }
#pragma unroll
        for (int c = 0; c < 8; c++) {
            size_t woff = (size_t)(c * 16 + lrow) * HH + kb;
            short8 whi = *(const short8*)(wt_hi + woff);
            short8 wlo = *(const short8*)(wt_lo + woff);
#pragma unroll
            for (int t = 0; t < 2; t++) {
                acc[t][c] = __builtin_amdgcn_mfma_f32_16x16x32_bf16(ahi[t], whi, acc[t][c], 0, 0, 0);
                acc[t][c] = __builtin_amdgcn_mfma_f32_16x16x32_bf16(alo[t], whi, acc[t][c], 0, 0, 0);
                acc[t][c] = __builtin_amdgcn_mfma_f32_16x16x32_bf16(ahi[t], wlo, acc[t][c], 0, 0, 0);
            }
        }
    }

    // C/D layout: col = c*16 + lrow, row (within 16-tile) = kgrp*4 + reg
    if (MODE == 0 || MODE == 1) {
#pragma unroll
        for (int c = 0; c < 8; c++) {
            int col = c * 16 + lrow;
            float bv = bias[col];
            float ps = 0.f, pq = 0.f;
#pragma unroll
            for (int t = 0; t < 2; t++)
#pragma unroll
                for (int reg = 0; reg < 4; reg++) {
                    int row = r0 + t * 16 + kgrp * 4 + reg;
                    if (row < NN) {
                        float z = acc[t][c][reg] + bv;
                        Out[(size_t)row * HH + col] = z;
                        if (MODE == 1) { ps += z; pq += z * z; }
                    }
                }
            if (MODE == 1) {
                atomicAdd(&csum[col], ps);
                atomicAdd(&csq[col], pq);
            }
        }
        if (MODE == 1) {
            __syncthreads();
            if (tid < HH) {
                atomicAdd(&colsum[tid], csum[tid]);
                atomicAdd(&colsq[tid], csq[tid]);
            }
        }
    } else {
        float bv[8], lg[8], lb[8];
#pragma unroll
        for (int c = 0; c < 8; c++) {
            int col = c * 16 + lrow;
            bv[c] = bias[col]; lg[c] = lng[col]; lb[c] = lnb[col];
        }
        // t_val = h_old + relu(z); overwrite acc with t_val
#pragma unroll
        for (int t = 0; t < 2; t++)
#pragma unroll
            for (int reg = 0; reg < 4; reg++) {
                int row = r0 + t * 16 + kgrp * 4 + reg;
#pragma unroll
                for (int c = 0; c < 8; c++) {
                    float z = fmaxf(acc[t][c][reg] + bv[c], 0.f);
                    float hold = (row < NN) ? Hbuf[(size_t)row * HH + c * 16 + lrow] : 0.f;
                    acc[t][c][reg] = hold + z;
                }
            }
        // per-row LN: reduce across 8 col-tiles in-thread, then across 16 lanes
#pragma unroll
        for (int t = 0; t < 2; t++)
#pragma unroll
            for (int reg = 0; reg < 4; reg++) {
                float s = 0.f, q = 0.f;
#pragma unroll
                for (int c = 0; c < 8; c++) { float v = acc[t][c][reg]; s += v; q += v * v; }
#pragma unroll
                for (int m = 1; m < 16; m <<= 1) {
                    s += __shfl_xor(s, m, 16);
                    q += __shfl_xor(q, m, 16);
                }
                float mu = s * (1.f / 128.f);
                float var = q * (1.f / 128.f) - mu * mu;
                float rs = rsqrtf(var + LN_EPS);
                int row = r0 + t * 16 + kgrp * 4 + reg;
                if (row < NN) {
#pragma unroll
                    for (int c = 0; c < 8; c++) {
                        Hbuf[(size_t)row * HH + c * 16 + lrow] =
                            (acc[t][c][reg] - mu) * rs * lg[c] + lb[c];
                    }
                }
            }
    }
}

__global__ void bn_finalize(const float* __restrict__ colsum, const float* __restrict__ colsq,
                            const float* __restrict__ bng, const float* __restrict__ bnb,
                            float* __restrict__ scale, float* __restrict__ shift)
{
    int c = threadIdx.x;
    float m = colsum[c] * (1.f / NN);
    float v = colsq[c] * (1.f / NN) - m * m;
    float a = bng[c] * rsqrtf(v + BN_EPS);
    scale[c] = a;
    shift[c] = bnb[c] - m * a;
}

// ---------------- pooling ----------------

__global__ void pool_kernel(const float* __restrict__ h, const int* __restrict__ batch,
                            float* __restrict__ psum, float* __restrict__ pcnt)
{
    int t = threadIdx.x;  // 128
    int n0 = blockIdx.x * POOL_CHUNK;
    int n1 = n0 + POOL_CHUNK; if (n1 > NN) n1 = NN;
    float acc = 0.f;
    int cur = batch[n0];
    int cnt = 0;
    for (int n = n0; n < n1; n++) {
        int g = batch[n];
        if (g != cur) {
            atomicAdd(&psum[cur * HH + t], acc);
            if (t == 0) atomicAdd(&pcnt[cur], (float)cnt);
            acc = 0.f; cnt = 0; cur = g;
        }
        acc += h[(size_t)n * HH + t];
        cnt++;
    }
    atomicAdd(&psum[cur * HH + t], acc);
    if (t == 0) atomicAdd(&pcnt[cur], (float)cnt);
}

__global__ void pool_final(const float* __restrict__ psum, const float* __restrict__ pcnt,
                           float* __restrict__ out)
{
    int i = blockIdx.x * blockDim.x + threadIdx.x;
    if (i < GG * HH) {
        float c = pcnt[i >> 7];
        out[i] = psum[i] / fmaxf(c, 1.f);
    }
}

// ---------------- launch ----------------

extern "C" void kernel_launch(void* const* d_in, const int* in_sizes, int n_in,
                              void* d_out, int out_size, void* d_ws, size_t ws_size,
                              hipStream_t stream)
{
    const float* x     = (const float*)d_in[0];
    const float* W0    = (const float*)d_in[1];
    const float* b0    = (const float*)d_in[2];
    const float* eps_l = (const float*)d_in[3];
    const float* W1    = (const float*)d_in[4];
    const float* b1    = (const float*)d_in[5];
    const float* bng   = (const float*)d_in[6];
    const float* bnb   = (const float*)d_in[7];
    const float* W2    = (const float*)d_in[8];
    const float* b2    = (const float*)d_in[9];
    const float* lng   = (const float*)d_in[10];
    const float* lnb   = (const float*)d_in[11];
    const int*   ei    = (const int*)d_in[12];
    const int*   batch = (const int*)d_in[13];
    float* out = (float*)d_out;

    char* ws = (char*)d_ws;
    size_t off = 0;
    auto alloc = [&](size_t bytes) -> void* {
        void* p = ws + off;
        off += (bytes + 255) & ~(size_t)255;
        return p;
    };
    float* hbuf   = (float*)alloc((size_t)NN * HH * 4);
    float* ubuf   = (float*)alloc((size_t)NN * HH * 4);
    int*   colidx = (int*)alloc((size_t)2 * EE * 4);
    int*   rp     = (int*)alloc((size_t)(NN + 1) * 4);
    int*   deg    = (int*)alloc((size_t)NN * 4);
    int*   cursor = (int*)alloc((size_t)NN * 4);
    int*   bsum   = (int*)alloc(128 * 4);
    int*   boff   = (int*)alloc(128 * 4);
    float* colsum = (float*)alloc(HH * 4);
    float* colsq  = (float*)alloc(HH * 4);
    float* bn_sc  = (float*)alloc(HH * 4);
    float* bn_sh  = (float*)alloc(HH * 4);
    float* psum   = (float*)alloc((size_t)GG * HH * 4);
    float* pcnt   = (float*)alloc(GG * 4);
    short* wt_hi  = (short*)alloc((size_t)9 * HH * HH * 2);
    short* wt_lo  = (short*)alloc((size_t)9 * HH * HH * 2);

    hipMemsetAsync(deg, 0, (size_t)NN * 4, stream);
    hipMemsetAsync(cursor, 0, (size_t)NN * 4, stream);
    hipMemsetAsync(psum, 0, (size_t)GG * HH * 4, stream);
    hipMemsetAsync(pcnt, 0, (size_t)GG * 4, stream);

    // weight prep (9 matrices -> transposed bf16 hi/lo)
    prep_w<<<(9 * HH * HH + 255) / 256, 256, 0, stream>>>(W0, W1, W2, wt_hi, wt_lo);

    // CSR build
    count_deg<<<(2 * EE + 255) / 256, 256, 0, stream>>>(ei, deg);
    scan_block<<<(NN + 1023) / 1024, 256, 0, stream>>>(deg, rp, bsum);
    scan_bsum<<<1, 128, 0, stream>>>(bsum, boff, rp + NN, (NN + 1023) / 1024);
    scan_add<<<(NN + 255) / 256, 256, 0, stream>>>(rp, boff);
    fill_csr<<<(2 * EE + 255) / 256, 256, 0, stream>>>(ei, rp, cursor, colidx);

    int gb = (NN + 127) / 128;
    // encode: h = x @ W0 + b0
    mfma_gemm<0><<<gb, 256, 0, stream>>>(x, wt_hi, wt_lo, b0, hbuf,
                                         nullptr, nullptr, nullptr, nullptr, nullptr, nullptr, nullptr);

    for (int l = 0; l < LL; l++) {
        agg_kernel<<<(NN + 3) / 4, 256, 0, stream>>>(hbuf, rp, colidx, eps_l, l, ubuf);
        hipMemsetAsync(colsum, 0, HH * 4, stream);
        hipMemsetAsync(colsq, 0, HH * 4, stream);
        // z1 = u @ W1 + b1 (in-place) + column stats
        mfma_gemm<1><<<gb, 256, 0, stream>>>(ubuf, wt_hi + (size_t)(1 + l) * HH * HH,
                                             wt_lo + (size_t)(1 + l) * HH * HH, b1 + l * HH, ubuf,
                                             colsum, colsq, nullptr, nullptr, nullptr, nullptr, nullptr);
        bn_finalize<<<1, 128, 0, stream>>>(colsum, colsq, bng + l * HH, bnb + l * HH, bn_sc, bn_sh);
        // h = LN(h + relu(relu(BN(z1)) @ W2 + b2))
        mfma_gemm<2><<<gb, 256, 0, stream>>>(ubuf, wt_hi + (size_t)(5 + l) * HH * HH,
                                             wt_lo + (size_t)(5 + l) * HH * HH, b2 + l * HH, nullptr,
                                             nullptr, nullptr, bn_sc, bn_sh,
                                             lng + l * HH, lnb + l * HH, hbuf);
    }

    pool_kernel<<<(NN + POOL_CHUNK - 1) / POOL_CHUNK, 128, 0, stream>>>(hbuf, batch, psum, pcnt);
    pool_final<<<(GG * HH + 255) / 256, 256, 0, stream>>>(psum, pcnt, out);
}

// Round 3
// 1067.798 us; speedup vs baseline: 1.6417x; 1.2671x over previous
//
#include <hip/hip_runtime.h>

#define NN 100000
#define EE 800000
#define HH 128
#define LL 4
#define GG 64
#define BN_EPS 1e-5f
#define LN_EPS 1e-5f
#define POOL_CHUNK 64
#define NBUK ((NN + 255) >> 8)   // 391 buckets of 256 rows
#define CAP 8192                 // LDS colidx staging capacity per bucket
#define BCHUNK 8192              // edges per block in scatter pass

typedef __attribute__((ext_vector_type(8))) short short8;
typedef __attribute__((ext_vector_type(4))) float f32x4;

__device__ inline unsigned short bf16_rne(float f) {
    unsigned u = __float_as_uint(f);
    return (unsigned short)((u + 0x7FFF + ((u >> 16) & 1)) >> 16);
}
__device__ inline float bf16_to_f32(unsigned short h) {
    return __uint_as_float((unsigned)h << 16);
}

// ---------------- CSR build: bucket sort (256 rows / bucket) ----------------

__global__ __launch_bounds__(256) void bucket_count(const int* __restrict__ ei, int* __restrict__ bcnt) {
    __shared__ int h[NBUK];
    int tid = threadIdx.x;
    for (int i = tid; i < NBUK; i += 256) h[i] = 0;
    __syncthreads();
    for (int e = blockIdx.x * 256 + tid; e < 2 * EE; e += gridDim.x * 256) {
        int r = ei[e];
        int c = (e < EE) ? ei[e + EE] : ei[e - EE];
        if (r != c) atomicAdd(&h[r >> 8], 1);
    }
    __syncthreads();
    for (int i = tid; i < NBUK; i += 256) if (h[i]) atomicAdd(&bcnt[i], h[i]);
}

__global__ void bucket_scan(const int* __restrict__ bcnt, int* __restrict__ bbase,
                            int* __restrict__ bcur, int* __restrict__ rp) {
    __shared__ int sh[512];
    int t = threadIdx.x;
    sh[t] = (t < NBUK) ? bcnt[t] : 0;
    __syncthreads();
    for (int off = 1; off < 512; off <<= 1) {
        int x = (t >= off) ? sh[t - off] : 0;
        __syncthreads();
        sh[t] += x;
        __syncthreads();
    }
    if (t < NBUK) {
        int excl = (t > 0) ? sh[t - 1] : 0;
        bbase[t] = excl;
        bcur[t] = excl;
    }
    if (t == NBUK - 1) {
        bbase[NBUK] = sh[t];
        rp[NN] = sh[t];
    }
}

__global__ __launch_bounds__(256) void bucket_scatter(const int* __restrict__ ei, int* __restrict__ bcur,
                                                      int* __restrict__ pairs) {
    __shared__ int h[NBUK];
    __shared__ int curb[NBUK];
    int tid = threadIdx.x;
    for (int i = tid; i < NBUK; i += 256) h[i] = 0;
    __syncthreads();
    int base = blockIdx.x * BCHUNK;
#pragma unroll 4
    for (int k = 0; k < BCHUNK / 256; k++) {
        int e = base + k * 256 + tid;
        if (e < 2 * EE) {
            int r = ei[e];
            int c = (e < EE) ? ei[e + EE] : ei[e - EE];
            if (r != c) atomicAdd(&h[r >> 8], 1);
        }
    }
    __syncthreads();
    for (int i = tid; i < NBUK; i += 256) {
        int n = h[i];
        curb[i] = n ? atomicAdd(&bcur[i], n) : 0;
    }
    __syncthreads();
#pragma unroll 4
    for (int k = 0; k < BCHUNK / 256; k++) {
        int e = base + k * 256 + tid;
        if (e < 2 * EE) {
            int r = ei[e];
            int c = (e < EE) ? ei[e + EE] : ei[e - EE];
            if (r != c) {
                int p = atomicAdd(&curb[r >> 8], 1);
                pairs[p] = ((r & 255) << 17) | c;
            }
        }
    }
}

__global__ __launch_bounds__(256) void bucket_build(const int* __restrict__ pairs, const int* __restrict__ bbase,
                                                    int* __restrict__ rp, int* __restrict__ colidx) {
    __shared__ int hist[256], off[256], lcol[CAP];
    int b = blockIdx.x, tid = threadIdx.x;
    int s = bbase[b];
    int size = bbase[b + 1] - s;
    hist[tid] = 0;
    __syncthreads();
    for (int i = tid; i < size; i += 256) atomicAdd(&hist[pairs[s + i] >> 17], 1);
    __syncthreads();
    off[tid] = hist[tid];
    __syncthreads();
    for (int o = 1; o < 256; o <<= 1) {
        int x = (tid >= o) ? off[tid - o] : 0;
        __syncthreads();
        off[tid] += x;
        __syncthreads();
    }
    int excl = (tid > 0) ? off[tid - 1] : 0;
    int r = (b << 8) + tid;
    if (r < NN) rp[r] = s + excl;
    hist[tid] = excl;  // reuse as cursor
    __syncthreads();
    if (size <= CAP) {
        for (int i = tid; i < size; i += 256) {
            int u = pairs[s + i];
            int p = atomicAdd(&hist[u >> 17], 1);
            lcol[p] = u & 0x1FFFF;
        }
        __syncthreads();
        for (int i = tid; i < size; i += 256) colidx[s + i] = lcol[i];
    } else {
        for (int i = tid; i < size; i += 256) {
            int u = pairs[s + i];
            int p = atomicAdd(&hist[u >> 17], 1);
            colidx[s + p] = u & 0x1FFFF;
        }
    }
}

// ---------------- weight prep: transpose + split fp32 -> bf16 hi/lo ----------------

__global__ void prep_w(const float* __restrict__ W0, const float* __restrict__ W1,
                       const float* __restrict__ W2,
                       short* __restrict__ wt_hi, short* __restrict__ wt_lo) {
    int i = blockIdx.x * 256 + threadIdx.x;
    if (i >= 9 * HH * HH) return;
    int mat = i >> 14, rem = i & 16383;
    int n = rem >> 7, k = rem & 127;
    const float* src = (mat == 0) ? W0 : ((mat <= 4) ? W1 + (size_t)(mat - 1) * HH * HH
                                                     : W2 + (size_t)(mat - 5) * HH * HH);
    float v = src[(size_t)k * HH + n];
    unsigned short h = bf16_rne(v);
    wt_hi[i] = (short)h;
    wt_lo[i] = (short)bf16_rne(v - bf16_to_f32(h));
}

// ---------------- aggregation: u = (1+eps)*h + sum_nb h[nb], gather from bf16 mirror ----------------

__global__ __launch_bounds__(256) void agg_kernel(
    const unsigned int* __restrict__ hbf, const int* __restrict__ rp, const int* __restrict__ colidx,
    const float* __restrict__ eps_l, int layer, float* __restrict__ u)
{
    int node = blockIdx.x * 4 + (threadIdx.x >> 6);
    if (node >= NN) return;
    int lane = threadIdx.x & 63;
    float eps1 = 1.0f + eps_l[layer];
    unsigned sv = hbf[node * 64 + lane];
    float ax = __uint_as_float(sv << 16) * eps1;
    float ay = __uint_as_float(sv & 0xFFFF0000u) * eps1;
    int i = rp[node], end = rp[node + 1];
    for (; i + 4 <= end; i += 4) {
        unsigned v0 = hbf[colidx[i] * 64 + lane];
        unsigned v1 = hbf[colidx[i + 1] * 64 + lane];
        unsigned v2 = hbf[colidx[i + 2] * 64 + lane];
        unsigned v3 = hbf[colidx[i + 3] * 64 + lane];
        ax += __uint_as_float(v0 << 16) + __uint_as_float(v1 << 16)
            + __uint_as_float(v2 << 16) + __uint_as_float(v3 << 16);
        ay += __uint_as_float(v0 & 0xFFFF0000u) + __uint_as_float(v1 & 0xFFFF0000u)
            + __uint_as_float(v2 & 0xFFFF0000u) + __uint_as_float(v3 & 0xFFFF0000u);
    }
    for (; i < end; i++) {
        unsigned v = hbf[colidx[i] * 64 + lane];
        ax += __uint_as_float(v << 16);
        ay += __uint_as_float(v & 0xFFFF0000u);
    }
    ((float2*)(u + (size_t)node * HH))[lane] = make_float2(ax, ay);
}

// ---------------- MFMA GEMM, split-bf16 (hi+lo), K=N=128 ----------------
// MODE 0: Out = A@W + bias; also write bf16 mirror hbf
// MODE 1: Out = A@W + bias, accumulate column sum/sumsq (BN stats)
// MODE 2: A' = relu(A*sc + sh);  Hbuf = LN(Hbuf + relu(A'@W + bias)); also write hbf

template<int MODE>
__global__ __launch_bounds__(256) void mfma_gemm(
    const float* __restrict__ A, const short* __restrict__ wt_hi, const short* __restrict__ wt_lo,
    const float* __restrict__ bias, float* __restrict__ Out,
    float* __restrict__ colsum, float* __restrict__ colsq,
    const float* __restrict__ sc, const float* __restrict__ sh,
    const float* __restrict__ lng, const float* __restrict__ lnb,
    float* __restrict__ Hbuf, unsigned short* __restrict__ hbf)
{
    __shared__ float csum[HH], csq[HH];
    int tid = threadIdx.x;
    int wave = tid >> 6, lane = tid & 63;
    int lrow = lane & 15, kgrp = lane >> 4;
    int r0 = blockIdx.x * 128 + wave * 32;
    if (MODE == 1) {
        if (tid < HH) { csum[tid] = 0.f; csq[tid] = 0.f; }
        __syncthreads();
    }
    f32x4 acc[2][8];
#pragma unroll
    for (int t = 0; t < 2; t++)
#pragma unroll
        for (int c = 0; c < 8; c++) acc[t][c] = (f32x4){0.f, 0.f, 0.f, 0.f};

#pragma unroll
    for (int ks = 0; ks < 4; ks++) {
        int kb = ks * 32 + kgrp * 8;
        float4 scv0, scv1, shv0, shv1;
        if (MODE == 2) {
            scv0 = *(const float4*)(sc + kb); scv1 = *(const float4*)(sc + kb + 4);
            shv0 = *(const float4*)(sh + kb); shv1 = *(const float4*)(sh + kb + 4);
        }
        short8 ahi[2], alo[2];
#pragma unroll
        for (int t = 0; t < 2; t++) {
            int row = r0 + t * 16 + lrow;
            float av[8];
            if (row < NN) {
                float4 p0 = *(const float4*)(A + (size_t)row * HH + kb);
                float4 p1 = *(const float4*)(A + (size_t)row * HH + kb + 4);
                av[0] = p0.x; av[1] = p0.y; av[2] = p0.z; av[3] = p0.w;
                av[4] = p1.x; av[5] = p1.y; av[6] = p1.z; av[7] = p1.w;
            } else {
#pragma unroll
                for (int j = 0; j < 8; j++) av[j] = 0.f;
            }
            if (MODE == 2) {
                av[0] = fmaxf(fmaf(av[0], scv0.x, shv0.x), 0.f);
                av[1] = fmaxf(fmaf(av[1], scv0.y, shv0.y), 0.f);
                av[2] = fmaxf(fmaf(av[2], scv0.z, shv0.z), 0.f);
                av[3] = fmaxf(fmaf(av[3], scv0.w, shv0.w), 0.f);
                av[4] = fmaxf(fmaf(av[4], scv1.x, shv1.x), 0.f);
                av[5] = fmaxf(fmaf(av[5], scv1.y, shv1.y), 0.f);
                av[6] = fmaxf(fmaf(av[6], scv1.z, shv1.z), 0.f);
                av[7] = fmaxf(fmaf(av[7], scv1.w, shv1.w), 0.f);
            }
#pragma unroll
            for (int j = 0; j < 8; j++) {
                unsigned short hb = bf16_rne(av[j]);
                ahi[t][j] = (short)hb;
                alo[t][j] = (short)bf16_rne(av[j] - bf16_to_f32(hb));
            }
        }
#pragma unroll
        for (int c = 0; c < 8; c++) {
            size_t woff = (size_t)(c * 16 + lrow) * HH + kb;
            short8 whi = *(const short8*)(wt_hi + woff);
            short8 wlo = *(const short8*)(wt_lo + woff);
#pragma unroll
            for (int t = 0; t < 2; t++) {
                acc[t][c] = __builtin_amdgcn_mfma_f32_16x16x32_bf16(ahi[t], whi, acc[t][c], 0, 0, 0);
                acc[t][c] = __builtin_amdgcn_mfma_f32_16x16x32_bf16(alo[t], whi, acc[t][c], 0, 0, 0);
                acc[t][c] = __builtin_amdgcn_mfma_f32_16x16x32_bf16(ahi[t], wlo, acc[t][c], 0, 0, 0);
            }
        }
    }

    // C/D layout: col = c*16 + lrow, row (within 16-tile) = kgrp*4 + reg
    if (MODE == 0 || MODE == 1) {
#pragma unroll
        for (int c = 0; c < 8; c++) {
            int col = c * 16 + lrow;
            float bv = bias[col];
            float ps = 0.f, pq = 0.f;
#pragma unroll
            for (int t = 0; t < 2; t++)
#pragma unroll
                for (int reg = 0; reg < 4; reg++) {
                    int row = r0 + t * 16 + kgrp * 4 + reg;
                    if (row < NN) {
                        float z = acc[t][c][reg] + bv;
                        Out[(size_t)row * HH + col] = z;
                        if (MODE == 0) hbf[(size_t)row * HH + col] = bf16_rne(z);
                        if (MODE == 1) { ps += z; pq += z * z; }
                    }
                }
            if (MODE == 1) {
                atomicAdd(&csum[col], ps);
                atomicAdd(&csq[col], pq);
            }
        }
        if (MODE == 1) {
            __syncthreads();
            if (tid < HH) {
                atomicAdd(&colsum[tid], csum[tid]);
                atomicAdd(&colsq[tid], csq[tid]);
            }
        }
    } else {
        float bv[8], lg[8], lb[8];
#pragma unroll
        for (int c = 0; c < 8; c++) {
            int col = c * 16 + lrow;
            bv[c] = bias[col]; lg[c] = lng[col]; lb[c] = lnb[col];
        }
#pragma unroll
        for (int t = 0; t < 2; t++)
#pragma unroll
            for (int reg = 0; reg < 4; reg++) {
                int row = r0 + t * 16 + kgrp * 4 + reg;
#pragma unroll
                for (int c = 0; c < 8; c++) {
                    float z = fmaxf(acc[t][c][reg] + bv[c], 0.f);
                    float hold = (row < NN) ? Hbuf[(size_t)row * HH + c * 16 + lrow] : 0.f;
                    acc[t][c][reg] = hold + z;
                }
            }
#pragma unroll
        for (int t = 0; t < 2; t++)
#pragma unroll
            for (int reg = 0; reg < 4; reg++) {
                float s = 0.f, q = 0.f;
#pragma unroll
                for (int c = 0; c < 8; c++) { float v = acc[t][c][reg]; s += v; q += v * v; }
#pragma unroll
                for (int m = 1; m < 16; m <<= 1) {
                    s += __shfl_xor(s, m, 16);
                    q += __shfl_xor(q, m, 16);
                }
                float mu = s * (1.f / 128.f);
                float var = q * (1.f / 128.f) - mu * mu;
                float rs = rsqrtf(var + LN_EPS);
                int row = r0 + t * 16 + kgrp * 4 + reg;
                if (row < NN) {
#pragma unroll
                    for (int c = 0; c < 8; c++) {
                        float o = (acc[t][c][reg] - mu) * rs * lg[c] + lb[c];
                        Hbuf[(size_t)row * HH + c * 16 + lrow] = o;
                        hbf[(size_t)row * HH + c * 16 + lrow] = bf16_rne(o);
                    }
                }
            }
    }
}

__global__ void bn_finalize(const float* __restrict__ colsum, const float* __restrict__ colsq,
                            const float* __restrict__ bng, const float* __restrict__ bnb,
                            float* __restrict__ scale, float* __restrict__ shift)
{
    int c = threadIdx.x;
    float m = colsum[c] * (1.f / NN);
    float v = colsq[c] * (1.f / NN) - m * m;
    float a = bng[c] * rsqrtf(v + BN_EPS);
    scale[c] = a;
    shift[c] = bnb[c] - m * a;
}

// ---------------- pooling ----------------

__global__ void pool_kernel(const float* __restrict__ h, const int* __restrict__ batch,
                            float* __restrict__ psum, float* __restrict__ pcnt)
{
    int t = threadIdx.x;  // 128
    int n0 = blockIdx.x * POOL_CHUNK;
    int n1 = n0 + POOL_CHUNK; if (n1 > NN) n1 = NN;
    if (n0 >= NN) return;
    float acc = 0.f;
    int cur = batch[n0];
    int cnt = 0;
    for (int n = n0; n < n1; n++) {
        int g = batch[n];
        if (g != cur) {
            atomicAdd(&psum[cur * HH + t], acc);
            if (t == 0) atomicAdd(&pcnt[cur], (float)cnt);
            acc = 0.f; cnt = 0; cur = g;
        }
        acc += h[(size_t)n * HH + t];
        cnt++;
    }
    atomicAdd(&psum[cur * HH + t], acc);
    if (t == 0) atomicAdd(&pcnt[cur], (float)cnt);
}

__global__ void pool_final(const float* __restrict__ psum, const float* __restrict__ pcnt,
                           float* __restrict__ out)
{
    int i = blockIdx.x * blockDim.x + threadIdx.x;
    if (i < GG * HH) {
        float c = pcnt[i >> 7];
        out[i] = psum[i] / fmaxf(c, 1.f);
    }
}

// ---------------- launch ----------------

extern "C" void kernel_launch(void* const* d_in, const int* in_sizes, int n_in,
                              void* d_out, int out_size, void* d_ws, size_t ws_size,
                              hipStream_t stream)
{
    const float* x     = (const float*)d_in[0];
    const float* W0    = (const float*)d_in[1];
    const float* b0    = (const float*)d_in[2];
    const float* eps_l = (const float*)d_in[3];
    const float* W1    = (const float*)d_in[4];
    const float* b1    = (const float*)d_in[5];
    const float* bng   = (const float*)d_in[6];
    const float* bnb   = (const float*)d_in[7];
    const float* W2    = (const float*)d_in[8];
    const float* b2    = (const float*)d_in[9];
    const float* lng   = (const float*)d_in[10];
    const float* lnb   = (const float*)d_in[11];
    const int*   ei    = (const int*)d_in[12];
    const int*   batch = (const int*)d_in[13];
    float* out = (float*)d_out;

    char* ws = (char*)d_ws;
    size_t off = 0;
    auto alloc = [&](size_t bytes) -> void* {
        void* p = ws + off;
        off += (bytes + 255) & ~(size_t)255;
        return p;
    };
    float* hbuf   = (float*)alloc((size_t)NN * HH * 4);
    float* ubuf   = (float*)alloc((size_t)NN * HH * 4);
    unsigned short* hbf = (unsigned short*)alloc((size_t)NN * HH * 2);
    int*   colidx = (int*)alloc((size_t)2 * EE * 4);
    int*   pairs  = (int*)alloc((size_t)2 * EE * 4);
    int*   rp     = (int*)alloc((size_t)(NN + 1) * 4);
    int*   bcnt   = (int*)alloc((NBUK + 1) * 4);
    int*   bbase  = (int*)alloc((NBUK + 1) * 4);
    int*   bcur   = (int*)alloc((NBUK + 1) * 4);
    float* colsum = (float*)alloc(HH * 4);
    float* colsq  = (float*)alloc(HH * 4);
    float* bn_sc  = (float*)alloc(HH * 4);
    float* bn_sh  = (float*)alloc(HH * 4);
    float* psum   = (float*)alloc((size_t)GG * HH * 4);
    float* pcnt   = (float*)alloc(GG * 4);
    short* wt_hi  = (short*)alloc((size_t)9 * HH * HH * 2);
    short* wt_lo  = (short*)alloc((size_t)9 * HH * HH * 2);

    hipMemsetAsync(bcnt, 0, (NBUK + 1) * 4, stream);
    hipMemsetAsync(psum, 0, (size_t)GG * HH * 4, stream);
    hipMemsetAsync(pcnt, 0, GG * 4, stream);

    // weight prep
    prep_w<<<(9 * HH * HH + 255) / 256, 256, 0, stream>>>(W0, W1, W2, wt_hi, wt_lo);

    // CSR build via bucket sort
    bucket_count<<<512, 256, 0, stream>>>(ei, bcnt);
    bucket_scan<<<1, 512, 0, stream>>>(bcnt, bbase, bcur, rp);
    bucket_scatter<<<(2 * EE + BCHUNK - 1) / BCHUNK, 256, 0, stream>>>(ei, bcur, pairs);
    bucket_build<<<NBUK, 256, 0, stream>>>(pairs, bbase, rp, colidx);

    int gb = (NN + 127) / 128;
    // encode: h = x @ W0 + b0
    mfma_gemm<0><<<gb, 256, 0, stream>>>(x, wt_hi, wt_lo, b0, hbuf,
                                         nullptr, nullptr, nullptr, nullptr, nullptr, nullptr,
                                         nullptr, hbf);

    for (int l = 0; l < LL; l++) {
        agg_kernel<<<(NN + 3) / 4, 256, 0, stream>>>((const unsigned int*)hbf, rp, colidx, eps_l, l, ubuf);
        hipMemsetAsync(colsum, 0, HH * 4, stream);
        hipMemsetAsync(colsq, 0, HH * 4, stream);
        mfma_gemm<1><<<gb, 256, 0, stream>>>(ubuf, wt_hi + (size_t)(1 + l) * HH * HH,
                                             wt_lo + (size_t)(1 + l) * HH * HH, b1 + l * HH, ubuf,
                                             colsum, colsq, nullptr, nullptr, nullptr, nullptr,
                                             nullptr, nullptr);
        bn_finalize<<<1, 128, 0, stream>>>(colsum, colsq, bng + l * HH, bnb + l * HH, bn_sc, bn_sh);
        mfma_gemm<2><<<gb, 256, 0, stream>>>(ubuf, wt_hi + (size_t)(5 + l) * HH * HH,
                                             wt_lo + (size_t)(5 + l) * HH * HH, b2 + l * HH, nullptr,
                                             nullptr, nullptr, bn_sc, bn_sh,
                                             lng + l * HH, lnb + l * HH, hbuf, hbf);
    }

    pool_kernel<<<(NN + POOL_CHUNK - 1) / POOL_CHUNK, 128, 0, stream>>>(hbuf, batch, psum, pcnt);
    pool_final<<<(GG * HH + 255) / 256, 256, 0, stream>>>(psum, pcnt, out);
}